// Round 7
// baseline (446.487 us; speedup 1.0000x reference)
//
#include <hip/hip_runtime.h>
#include <hip/hip_bf16.h>
#include <math.h>

// Problem constants (fixed by the reference)
#define HEADS 32
#define DIM_HEAD 64
#define DM 2048          // HEADS * DIM_HEAD
#define BATCH 2
#define SEQ 1024
#define NROWS (BATCH * SEQ)      // 2048 rows of DM
#define NVEC (NROWS * HEADS)     // 65536 per-head vectors
#define N_GROUPS 22
#define N_LEVELS 8
#define EPS_NORM 1e-8f
#define EPS_RMS 1e-6f

typedef float f32x4 __attribute__((ext_vector_type(4)));
typedef __bf16 bf16x8 __attribute__((ext_vector_type(8)));
typedef unsigned short u16x8 __attribute__((ext_vector_type(8)));
typedef unsigned short u16x4 __attribute__((ext_vector_type(4)));

// base-2 exp: v_exp_f32 is natively 2^x on gfx950
#if __has_builtin(__builtin_amdgcn_exp2f)
#define EXP2F(x) __builtin_amdgcn_exp2f(x)
#else
#define EXP2F(x) exp2f(x)
#endif

__device__ __forceinline__ unsigned short f2bf(float x) {
  union { float f; unsigned u; } v; v.f = x;
  unsigned r = v.u + 0x7fffu + ((v.u >> 16) & 1u);  // RTN-even
  return (unsigned short)(r >> 16);
}
__device__ __forceinline__ float bf2f(unsigned short h) {
  union { unsigned u; float f; } v; v.u = ((unsigned)h) << 16;
  return v.f;
}
__device__ __forceinline__ bf16x8 ldfrag(const unsigned short* p) {
  return __builtin_bit_cast(bf16x8, *(const u16x8*)p);
}
#define MFMA16(a, b, c) __builtin_amdgcn_mfma_f32_16x16x32_bf16((a), (b), (c), 0, 0, 0)

__device__ __forceinline__ void stage16(const unsigned short* g, unsigned short* lds) {
  __builtin_amdgcn_global_load_lds(
      (const __attribute__((address_space(1))) unsigned int*)g,
      (__attribute__((address_space(3))) unsigned int*)lds, 16, 0, 0);
}

// Pipeline control (attention): raw barrier, counted vmcnt, sched fence.
#define WAITV(N) asm volatile("s_waitcnt vmcnt(" #N ")" ::: "memory")
#define SBARM()  asm volatile("s_barrier" ::: "memory")
#define SFENCE() __builtin_amdgcn_sched_barrier(0)

// ---------------------------------------------------------------------------
// fp32 -> bf16 hi/lo split (lo optional), 8 elements/thread
// ---------------------------------------------------------------------------
__global__ __launch_bounds__(256) void split_convert_kernel(
    const float* __restrict__ X, unsigned short* __restrict__ hi,
    unsigned short* __restrict__ lo, int n8) {
  const int i = blockIdx.x * 256 + threadIdx.x;
  if (i >= n8) return;
  const float4 a = ((const float4*)X)[2 * i];
  const float4 b = ((const float4*)X)[2 * i + 1];
  const float v[8] = {a.x, a.y, a.z, a.w, b.x, b.y, b.z, b.w};
  u16x8 h, l;
#pragma unroll
  for (int j = 0; j < 8; ++j) {
    const unsigned short hh = f2bf(v[j]);
    h[j] = hh;
    l[j] = f2bf(v[j] - bf2f(hh));
  }
  ((u16x8*)hi)[i] = h;
  if (lo) ((u16x8*)lo)[i] = l;
}

// ---------------------------------------------------------------------------
// Batched weight transpose+split: W [K][M] fp32 -> T [M][K] bf16 hi(/lo).
// grid (M/64, K/64, 4): z selects {Wq, Wk, Wv, Wo}.
// ---------------------------------------------------------------------------
__global__ __launch_bounds__(256) void transpose_split_batch_kernel(
    const float* __restrict__ W0, const float* __restrict__ W1,
    const float* __restrict__ W2, const float* __restrict__ W3,
    unsigned short* __restrict__ T0h, unsigned short* __restrict__ T1h,
    unsigned short* __restrict__ T1l, unsigned short* __restrict__ T2h,
    unsigned short* __restrict__ T2l, unsigned short* __restrict__ T3h) {
  const int z = blockIdx.z;
  const float* W = (z == 0) ? W0 : (z == 1) ? W1 : (z == 2) ? W2 : W3;
  unsigned short* Th = (z == 0) ? T0h : (z == 1) ? T1h : (z == 2) ? T2h : T3h;
  unsigned short* Tl = (z == 1) ? T1l : (z == 2) ? T2l : nullptr;

  __shared__ float S[64][65];
  const int t = threadIdx.x;
  const int tk = blockIdx.y * 64, tm = blockIdx.x * 64;
  {
    const int r = t >> 2, cs = (t & 3) * 16;
    const float* src = W + (size_t)(tk + r) * DM + tm + cs;
#pragma unroll
    for (int j = 0; j < 16; j += 4) {
      float4 v = *(const float4*)(src + j);
      S[r][cs + j] = v.x; S[r][cs + j + 1] = v.y;
      S[r][cs + j + 2] = v.z; S[r][cs + j + 3] = v.w;
    }
  }
  __syncthreads();
  const int m = t >> 2, ks = (t & 3) * 16;
  u16x8 h0, h1, l0, l1;
#pragma unroll
  for (int j = 0; j < 8; ++j) {
    const float v = S[ks + j][m];
    const unsigned short hh = f2bf(v);
    h0[j] = hh; l0[j] = f2bf(v - bf2f(hh));
  }
#pragma unroll
  for (int j = 0; j < 8; ++j) {
    const float v = S[ks + 8 + j][m];
    const unsigned short hh = f2bf(v);
    h1[j] = hh; l1[j] = f2bf(v - bf2f(hh));
  }
  const size_t o = (size_t)(tm + m) * DM + tk + ks;
  *(u16x8*)&Th[o] = h0; *(u16x8*)&Th[o + 8] = h1;
  if (Tl) { *(u16x8*)&Tl[o] = l0; *(u16x8*)&Tl[o + 8] = l1; }
}

// ---------------------------------------------------------------------------
// Fused QKV GEMM: A[N=2048][K=2048] @ Bcat[M=6144][K]^T.
// Segments: 0..2047 Wq^T (plain), 2048..4095 Wk^T, 4096..6143 Wv^T (split).
// ROUND-7 CHANGE: tile 128x256 (was 128x128), 4 waves, per-wave 64x128
// (acc 4x8). Cuts ds_read traffic per MFMA by 27% (24 b128 reads / 96 MFMA
// = 0.25 vs 0.33) — the measured 43% MfmaUtil ceiling was LDS-BW-bound.
// Same proven 2-barrier drain loop + (row>>1)&3 two-sided swizzle. Grid
// 24x16=384; q-seg blocks do 1/3 the MFMA of k/v blocks (self-balancing).
// VGPR ~224 -> launch_bounds(256,2): 2 waves/SIMD, 2 blocks/CU (48 KB LDS).
// ---------------------------------------------------------------------------
__global__ __launch_bounds__(256, 2) void qkv_gemm_kernel(
    const unsigned short* __restrict__ Ahi, const unsigned short* __restrict__ Alo,
    const unsigned short* __restrict__ Bhi, const unsigned short* __restrict__ Blo,
    float* __restrict__ q, float* __restrict__ k, float* __restrict__ v) {
  __shared__ unsigned short lAhi[128 * 32];
  __shared__ unsigned short lAlo[128 * 32];
  __shared__ unsigned short lBhi[256 * 32];
  __shared__ unsigned short lBlo[256 * 32];

  const int t = threadIdx.x;
  const int lane = t & 63, wave = t >> 6;
  const int wr = wave >> 1, wc = wave & 1;
  const int gm0 = blockIdx.y * 128;
  const int gnc = blockIdx.x * 256;
  const int seg = gnc >> 11;
  const bool split = (seg != 0);
  const int quad = lane >> 4, l15 = lane & 15;
  const int srow = lane >> 2, schunk = lane & 3;

  f32x4 acc[4][8] = {};

  for (int kt = 0; kt < DM; kt += 32) {
    __syncthreads();
    // ---- stage A [128][32] (2 loads/thread/array)
#pragma unroll
    for (int it = 0; it < 2; ++it) {
      const int g = it * 4 + wave;             // 0..7
      const int r = g * 16 + srow;
      const int c = schunk ^ ((r >> 1) & 3);
      const size_t go = (size_t)(gm0 + r) * DM + kt + c * 8;
      stage16(Ahi + go, lAhi + g * 512);
      if (split) stage16(Alo + go, lAlo + g * 512);
    }
    // ---- stage B [256][32] (4 loads/thread/array)
#pragma unroll
    for (int it = 0; it < 4; ++it) {
      const int g = it * 4 + wave;             // 0..15
      const int r = g * 16 + srow;
      const int c = schunk ^ ((r >> 1) & 3);
      const size_t go = (size_t)(gnc + r) * DM + kt + c * 8;
      stage16(Bhi + go, lBhi + g * 512);
      if (split) stage16(Blo + go, lBlo + g * 512);
    }
    __syncthreads();

    bf16x8 ah[4], bh[8];
#pragma unroll
    for (int i = 0; i < 4; ++i) {
      const int row = wr * 64 + i * 16 + l15;
      ah[i] = ldfrag(&lAhi[row * 32 + ((quad ^ ((row >> 1) & 3)) << 3)]);
    }
#pragma unroll
    for (int j = 0; j < 8; ++j) {
      const int row = wc * 128 + j * 16 + l15;
      bh[j] = ldfrag(&lBhi[row * 32 + ((quad ^ ((row >> 1) & 3)) << 3)]);
    }
#pragma unroll
    for (int i = 0; i < 4; ++i)
#pragma unroll
      for (int j = 0; j < 8; ++j)
        acc[i][j] = MFMA16(ah[i], bh[j], acc[i][j]);

    if (split) {
      bf16x8 bl[8];
#pragma unroll
      for (int j = 0; j < 8; ++j) {
        const int row = wc * 128 + j * 16 + l15;
        bl[j] = ldfrag(&lBlo[row * 32 + ((quad ^ ((row >> 1) & 3)) << 3)]);
      }
#pragma unroll
      for (int i = 0; i < 4; ++i)
#pragma unroll
        for (int j = 0; j < 8; ++j)
          acc[i][j] = MFMA16(ah[i], bl[j], acc[i][j]);
      bf16x8 al[4];
#pragma unroll
      for (int i = 0; i < 4; ++i) {
        const int row = wr * 64 + i * 16 + l15;
        al[i] = ldfrag(&lAlo[row * 32 + ((quad ^ ((row >> 1) & 3)) << 3)]);
      }
#pragma unroll
      for (int i = 0; i < 4; ++i)
#pragma unroll
        for (int j = 0; j < 8; ++j)
          acc[i][j] = MFMA16(al[i], bh[j], acc[i][j]);
    }
  }

  float* C = (seg == 0) ? q : (seg == 1) ? k : v;
  const int gn0 = gnc & 2047;
#pragma unroll
  for (int i = 0; i < 4; ++i) {
    const int row = gm0 + wr * 64 + i * 16 + (quad << 2);
#pragma unroll
    for (int j = 0; j < 8; ++j) {
      const int col = gn0 + wc * 128 + j * 16 + l15;
#pragma unroll
      for (int r = 0; r < 4; ++r)
        C[(size_t)(row + r) * DM + col] = acc[i][j][r];
    }
  }
}

// ---------------------------------------------------------------------------
// Output projection, split-K=2 (plain bf16), partials into Cpart.
// ---------------------------------------------------------------------------
__global__ __launch_bounds__(256) void gemm_out_splitk_kernel(
    const unsigned short* __restrict__ Ahi, const unsigned short* __restrict__ Bt,
    float* __restrict__ Cpart) {
  __shared__ unsigned short lAhi[128 * 32];
  __shared__ unsigned short lBhi[128 * 32];

  const int t = threadIdx.x;
  const int lane = t & 63, wave = t >> 6;
  const int wr = wave >> 1, wc = wave & 1;
  const int gm0 = blockIdx.y * 128, gn0 = blockIdx.x * 128;
  const int z = blockIdx.z;
  const int k0 = z * (DM / 2);
  const int lrsub = lane >> 2;
  const int lcsub = lane & 3;

  f32x4 acc[4][4] = {};

  for (int kt = k0; kt < k0 + DM / 2; kt += 32) {
    __syncthreads();
#pragma unroll
    for (int rg = wave; rg < 8; rg += 4) {
      const int lrow = rg * 16 + lrsub;
      const int c = lcsub ^ ((lrow >> 1) & 3);
      stage16(Ahi + (size_t)(gm0 + lrow) * DM + kt + c * 8, lAhi + rg * 512);
      stage16(Bt + (size_t)(gn0 + lrow) * DM + kt + c * 8, lBhi + rg * 512);
    }
    __syncthreads();

    bf16x8 ah[4], bh[4];
#pragma unroll
    for (int i = 0; i < 4; ++i) {
      const int mrow = wr * 64 + i * 16 + (lane & 15);
      ah[i] = ldfrag(&lAhi[mrow * 32 + (((lane >> 4) ^ ((mrow >> 1) & 3)) << 3)]);
      const int nrow = wc * 64 + i * 16 + (lane & 15);
      bh[i] = ldfrag(&lBhi[nrow * 32 + (((lane >> 4) ^ ((nrow >> 1) & 3)) << 3)]);
    }
#pragma unroll
    for (int i = 0; i < 4; ++i)
#pragma unroll
      for (int j = 0; j < 4; ++j)
        acc[i][j] = MFMA16(ah[i], bh[j], acc[i][j]);
  }

  float* C = Cpart + (size_t)z * NROWS * DM;
#pragma unroll
  for (int i = 0; i < 4; ++i) {
    const int row = gm0 + wr * 64 + i * 16 + ((lane >> 4) << 2);
#pragma unroll
    for (int j = 0; j < 4; ++j) {
      const int col = gn0 + wc * 64 + j * 16 + (lane & 15);
#pragma unroll
      for (int r = 0; r < 4; ++r)
        C[(size_t)(row + r) * DM + col] = acc[i][j][r];
    }
  }
}

__global__ __launch_bounds__(256) void add2_f4_kernel(
    const float* __restrict__ a, const float* __restrict__ b,
    float* __restrict__ o, int n4) {
  const int i = blockIdx.x * 256 + threadIdx.x;
  if (i >= n4) return;
  const float4 x = ((const float4*)a)[i];
  const float4 y = ((const float4*)b)[i];
  ((float4*)o)[i] = make_float4(x.x + y.x, x.y + y.y, x.z + y.z, x.w + y.w);
}

// ---------------------------------------------------------------------------
// Wave reductions
// ---------------------------------------------------------------------------
__device__ __forceinline__ float wave_sum(float x) {
#pragma unroll
  for (int o = 32; o > 0; o >>= 1) x += __shfl_xor(x, o, 64);
  return x;
}

// ---------------------------------------------------------------------------
// RMSNorm in place (fp32), one block per row.  (k path)
// ---------------------------------------------------------------------------
__global__ __launch_bounds__(256) void rmsnorm_kernel(
    float* __restrict__ y, const float* __restrict__ w) {
  __shared__ float rbuf[4];
  const int row = blockIdx.x;
  float* p = y + (size_t)row * DM;
  const int t = threadIdx.x;
  const int wave = t >> 6, lane = t & 63;

  float ss = 0.f;
#pragma unroll
  for (int c = t; c < DM; c += 256) { float v = p[c]; ss += v * v; }
  ss = wave_sum(ss);
  if (lane == 0) rbuf[wave] = ss;
  __syncthreads();
  ss = rbuf[0] + rbuf[1] + rbuf[2] + rbuf[3];
  const float scale = rsqrtf(ss * (1.0f / DM) + EPS_RMS);
#pragma unroll
  for (int c = t; c < DM; c += 256) p[c] = p[c] * scale * w[c];
}

// ---------------------------------------------------------------------------
// RMSNorm -> bf16 hi/lo with extra post-scale (q path: folds 1/8 * log2e)
// ---------------------------------------------------------------------------
__global__ __launch_bounds__(256) void rmsnorm_split_kernel(
    const float* __restrict__ y, const float* __restrict__ w,
    unsigned short* __restrict__ hi, unsigned short* __restrict__ lo,
    float post) {
  __shared__ float rbuf[4];
  const int row = blockIdx.x;
  const float* p = y + (size_t)row * DM;
  const int t = threadIdx.x;
  const int wave = t >> 6, lane = t & 63;

  const int c0 = t * 8;
  float4 a = *(const float4*)(p + c0);
  float4 b = *(const float4*)(p + c0 + 4);
  float v[8] = {a.x, a.y, a.z, a.w, b.x, b.y, b.z, b.w};
  float ss = 0.f;
#pragma unroll
  for (int j = 0; j < 8; ++j) ss += v[j] * v[j];
  ss = wave_sum(ss);
  if (lane == 0) rbuf[wave] = ss;
  __syncthreads();
  ss = rbuf[0] + rbuf[1] + rbuf[2] + rbuf[3];
  const float scale = rsqrtf(ss * (1.0f / DM) + EPS_RMS) * post;

  u16x8 hv, lv;
#pragma unroll
  for (int j = 0; j < 8; ++j) {
    const float val = v[j] * scale * w[c0 + j];
    const unsigned short hh = f2bf(val);
    hv[j] = hh; lv[j] = f2bf(val - bf2f(hh));
  }
  *(u16x8*)&hi[(size_t)row * DM + c0] = hv;
  *(u16x8*)&lo[(size_t)row * DM + c0] = lv;
}

// ---------------------------------------------------------------------------
// RotorQuant roundtrip. WRITE_BF: emit bf16 hi/lo; else fp32 in place.
// ---------------------------------------------------------------------------
__device__ __forceinline__ float qnearest(float v, const float* __restrict__ C) {
  float best = C[0];
  float bd = fabsf(v - C[0]);
#pragma unroll
  for (int i = 1; i < N_LEVELS; ++i) {
    float d = fabsf(v - C[i]);
    if (d < bd) { bd = d; best = C[i]; }
  }
  return best;
}

template <bool WRITE_BF>
__global__ __launch_bounds__(256) void quant_kernel(
    float* __restrict__ kv, const float* __restrict__ M,
    const float* __restrict__ Mt, const float* __restrict__ C,
    unsigned short* __restrict__ hi, unsigned short* __restrict__ lo) {
  const int vec = blockIdx.x * blockDim.x + threadIdx.x;
  if (vec >= NVEC) return;
  float* p = kv + (size_t)vec * DIM_HEAD;

  float h[66];
  float ss = 0.f;
#pragma unroll
  for (int d = 0; d < DIM_HEAD; ++d) { h[d] = p[d]; ss += h[d] * h[d]; }
  float norm = fmaxf(sqrtf(ss), EPS_NORM);
  const float inv = 1.0f / norm;
#pragma unroll
  for (int d = 0; d < DIM_HEAD; ++d) h[d] *= inv;
  h[64] = 0.f; h[65] = 0.f;

#pragma unroll
  for (int g = 0; g < N_GROUPS; ++g) {
    const float* Mg  = M  + g * 9;
    const float* Mtg = Mt + g * 9;
    const float a0 = h[3 * g + 0], a1 = h[3 * g + 1], a2 = h[3 * g + 2];
    const float r0 = a0 * Mg[0] + a1 * Mg[3] + a2 * Mg[6];
    const float r1 = a0 * Mg[1] + a1 * Mg[4] + a2 * Mg[7];
    const float r2 = a0 * Mg[2] + a1 * Mg[5] + a2 * Mg[8];
    const float d0 = qnearest(r0, C);
    const float d1 = qnearest(r1, C);
    const float d2 = qnearest(r2, C);
    h[3 * g + 0] = d0 * Mtg[0] + d1 * Mtg[3] + d2 * Mtg[6];
    h[3 * g + 1] = d0 * Mtg[1] + d1 * Mtg[4] + d2 * Mtg[7];
    h[3 * g + 2] = d0 * Mtg[2] + d1 * Mtg[5] + d2 * Mtg[8];
  }
  if (WRITE_BF) {
#pragma unroll
    for (int g8 = 0; g8 < 8; ++g8) {
      u16x8 hv, lv;
#pragma unroll
      for (int j = 0; j < 8; ++j) {
        const float val = h[g8 * 8 + j] * norm;
        const unsigned short hh = f2bf(val);
        hv[j] = hh; lv[j] = f2bf(val - bf2f(hh));
      }
      *(u16x8*)&hi[(size_t)vec * DIM_HEAD + g8 * 8] = hv;
      *(u16x8*)&lo[(size_t)vec * DIM_HEAD + g8 * 8] = lv;
    }
  } else {
#pragma unroll
    for (int d = 0; d < DIM_HEAD; ++d) p[d] = h[d] * norm;
  }
}

// ---------------------------------------------------------------------------
// Per-head V transpose + split: v[b][s][h*64+d] fp32 -> vt[(bh*64+d)][s] hi/lo
// ---------------------------------------------------------------------------
__global__ __launch_bounds__(256) void vt_split_kernel(
    const float* __restrict__ v, unsigned short* __restrict__ hi,
    unsigned short* __restrict__ lo) {
  __shared__ float T[64][65];
  const int s0 = blockIdx.x * 64;
  const int bh = blockIdx.y;
  const int b = bh >> 5, h = bh & 31;
  const int t = threadIdx.x;
  {
    const int sr = t >> 2, dseg = (t & 3) * 16;
    const float* src = v + ((size_t)(b * SEQ + s0 + sr) * DM + h * 64 + dseg);
#pragma unroll
    for (int j = 0; j < 16; j += 4) {
      float4 a = *(const float4*)(src + j);
      T[sr][dseg + j] = a.x; T[sr][dseg + j + 1] = a.y;
      T[sr][dseg + j + 2] = a.z; T[sr][dseg + j + 3] = a.w;
    }
  }
  __syncthreads();
  const int d = t >> 2, sseg = (t & 3) * 16;
  u16x8 h0, h1, l0, l1;
#pragma unroll
  for (int j = 0; j < 8; ++j) {
    const float val = T[sseg + j][d];
    const unsigned short hh = f2bf(val);
    h0[j] = hh; l0[j] = f2bf(val - bf2f(hh));
  }
#pragma unroll
  for (int j = 0; j < 8; ++j) {
    const float val = T[sseg + 8 + j][d];
    const unsigned short hh = f2bf(val);
    h1[j] = hh; l1[j] = f2bf(val - bf2f(hh));
  }
  const size_t o = (size_t)(bh * 64 + d) * SEQ + s0 + sseg;
  *(u16x8*)&hi[o] = h0; *(u16x8*)&hi[o + 8] = h1;
  *(u16x8*)&lo[o] = l0; *(u16x8*)&lo[o + 8] = l1;
}

// ---------------------------------------------------------------------------
// MFMA flash attention, split-bf16. Block = (b,h,64 q rows), 256 threads.
// Swapped QK^T (S^T layout, lane-local softmax), conflict-free P-LDS,
// exp2 domain, K/V dbuf + counted vmcnt + raw barriers. 80 KB LDS.
// (round-6 verified: 441 µs end-to-end, attn no longer top dispatch)
// ---------------------------------------------------------------------------
__global__ __launch_bounds__(256) void attn_mfma_kernel(
    const unsigned short* __restrict__ qhi, const unsigned short* __restrict__ qlo,
    const unsigned short* __restrict__ khi, const unsigned short* __restrict__ klo,
    const unsigned short* __restrict__ vthi, const unsigned short* __restrict__ vtlo,
    unsigned short* __restrict__ ohi) {
  __shared__ unsigned short Ks_h[2][4096], Ks_l[2][4096];   // [buf][64 key][64 d]
  __shared__ unsigned short Vt_h[2][4096], Vt_l[2][4096];   // [buf][64 d][64 s]
  __shared__ unsigned int   Ps[4096];                       // [4 w][16 q][64 key]

  const int bh = blockIdx.x;        // 0..63  (XCD = bh % 8 -> L2 locality)
  const int qt = blockIdx.y;        // 0..15
  const int h = bh & 31, b = bh >> 5;
  const int q0 = qt * 64;
  const int t = threadIdx.x, lane = t & 63, w = t >> 6;
  const int quad = lane >> 4, l15 = lane & 15;
  const int srow = lane >> 3, schunk = lane & 7;
  const int pswz = (l15 & 7) << 2;            // P swizzle (words, 16B-multiple)
  unsigned int* Psw = Ps + w * 1024;          // wave-private [16][64] u32

  auto stage = [&](const unsigned short* g, int stride, unsigned short* arr) {
#pragma unroll
    for (int it = 0; it < 2; ++it) {
      const int r = w * 16 + it * 8 + srow;
      const int c = schunk ^ (r & 7);
      stage16(g + (size_t)r * stride + c * 8, arr + (w * 16 + it * 8) * 64);
    }
  };

  const unsigned short* gkh = khi + ((size_t)(b * SEQ) * DM + h * 64);
  const unsigned short* gkl = klo + ((size_t)(b * SEQ) * DM + h * 64);
  const unsigned short* gvh = vthi + (size_t)(bh * 64) * SEQ;
  const unsigned short* gvl = vtlo + (size_t)(bh * 64) * SEQ;

  auto stageAll = [&](int kt, int buf) {
    stage(gkh + (size_t)kt * DM, DM, Ks_h[buf]);
    stage(gkl + (size_t)kt * DM, DM, Ks_l[buf]);
    stage(gvh + kt, SEQ, Vt_h[buf]);
    stage(gvl + kt, SEQ, Vt_l[buf]);
  };

  // Q frags (B-operand of swapped QK: col n = l15 = q row; same lane map)
  bf16x8 qh[2], ql[2];
  {
    const size_t qrow = (size_t)(b * SEQ + q0 + w * 16 + l15) * DM + h * 64;
#pragma unroll
    for (int ks = 0; ks < 2; ++ks) {
      qh[ks] = ldfrag(&qhi[qrow + ks * 32 + quad * 8]);
      ql[ks] = ldfrag(&qlo[qrow + ks * 32 + quad * 8]);
    }
  }

  f32x4 acc[4] = {};               // O^T: row d = mt*16+quad*4+r, col q = l15
  float m_prev = -INFINITY;        // per-lane (q = l15); replicated across quads
  float lsum = 0.f;

  stageAll(0, 0);

  for (int tt = 0; tt < 16; ++tt) {
    const int c = tt & 1, n = c ^ 1;
    if (tt < 15) {
      stageAll((tt + 1) * 64, n);
      WAITV(8);
    } else {
      WAITV(0);
    }
    SBARM(); SFENCE();
    const unsigned short* cKh = Ks_h[c];
    const unsigned short* cKl = Ks_l[c];
    const unsigned short* cVh = Vt_h[c];
    const unsigned short* cVl = Vt_l[c];

    // ---- S^T = K @ Q (swapped), split: Kh*Qh + Kl*Qh + Kh*Ql
    f32x4 s[4] = {};
    __builtin_amdgcn_s_setprio(1);
#pragma unroll
    for (int nt = 0; nt < 4; ++nt) {
#pragma unroll
      for (int ks = 0; ks < 2; ++ks) {
        const int row = nt * 16 + l15;
        const int off = row * 64 + (((quad + 4 * ks) ^ (row & 7)) << 3);
        const bf16x8 kh = ldfrag(&cKh[off]);
        const bf16x8 kl = ldfrag(&cKl[off]);
        s[nt] = MFMA16(kh, qh[ks], s[nt]);
        s[nt] = MFMA16(kl, qh[ks], s[nt]);
        s[nt] = MFMA16(kh, ql[ks], s[nt]);
      }
    }
    __builtin_amdgcn_s_setprio(0);

    // ---- online softmax, lane-local over 16 keys + 2 cross-quad shuffles
    float mx = s[0][0];
#pragma unroll
    for (int nt = 0; nt < 4; ++nt)
#pragma unroll
      for (int r = 0; r < 4; ++r) mx = fmaxf(mx, s[nt][r]);
    mx = fmaxf(mx, __shfl_xor(mx, 16, 64));
    mx = fmaxf(mx, __shfl_xor(mx, 32, 64));
    const float mn = fmaxf(m_prev, mx);
    const float al = EXP2F(m_prev - mn);
    float rs = 0.f;
#pragma unroll
    for (int nt = 0; nt < 4; ++nt)
#pragma unroll
      for (int r = 0; r < 4; ++r) {
        const float e = EXP2F(s[nt][r] - mn);
        s[nt][r] = e; rs += e;
      }
    rs += __shfl_xor(rs, 16, 64);
    rs += __shfl_xor(rs, 32, 64);
    lsum = lsum * al + rs;
    m_prev = mn;
#pragma unroll
    for (int mt = 0; mt < 4; ++mt) acc[mt] *= al;   // acc col q = l15: lane-local

    // ---- P store: row = q (l15), col = key = nt*16 + quad*4 + r, packed
    //      hi|lo u32, one b128 per nt, swizzled col ^ pswz (conflict-free)
#pragma unroll
    for (int nt = 0; nt < 4; ++nt) {
      uint4 pw;
      unsigned int* wp = (unsigned int*)&pw;
#pragma unroll
      for (int r = 0; r < 4; ++r) {
        const unsigned short hh = f2bf(s[nt][r]);
        const unsigned short ll = f2bf(s[nt][r] - bf2f(hh));
        wp[r] = ((unsigned)hh << 16) | (unsigned)ll;
      }
      const int cb = (nt * 16 + quad * 4) ^ pswz;
      *(uint4*)&Psw[l15 * 64 + cb] = pw;
    }

    // ---- P load as B-frag (col q = l15, k = key = ks*32 + quad*8 + j)
    bf16x8 ph[2], pl[2];
#pragma unroll
    for (int ks = 0; ks < 2; ++ks) {
      const int c0 = (ks * 32 + quad * 8) ^ pswz;
      const int c1 = (ks * 32 + quad * 8 + 4) ^ pswz;
      const uint4 pa = *(const uint4*)&Psw[l15 * 64 + c0];
      const uint4 pb = *(const uint4*)&Psw[l15 * 64 + c1];
      u16x8 hv, lv;
      const unsigned int pw[8] = {pa.x, pa.y, pa.z, pa.w, pb.x, pb.y, pb.z, pb.w};
#pragma unroll
      for (int j = 0; j < 8; ++j) {
        hv[j] = (unsigned short)(pw[j] >> 16);
        lv[j] = (unsigned short)(pw[j] & 0xffffu);
      }
      ph[ks] = __builtin_bit_cast(bf16x8, hv);
      pl[ks] = __builtin_bit_cast(bf16x8, lv);
    }

    // ---- O^T += V^T @ P  (A = Vt frags, B = P frags)
    __builtin_amdgcn_s_setprio(1);
#pragma unroll
    for (int mt = 0; mt < 4; ++mt) {
#pragma unroll
      for (int ks = 0; ks < 2; ++ks) {
        const int drow = mt * 16 + l15;
        const int offv = drow * 64 + (((quad + 4 * ks) ^ (drow & 7)) << 3);
        const bf16x8 vh = ldfrag(&cVh[offv]);
        const bf16x8 vl = ldfrag(&cVl[offv]);
        acc[mt] = MFMA16(vh, ph[ks], acc[mt]);
        acc[mt] = MFMA16(vh, pl[ks], acc[mt]);
        acc[mt] = MFMA16(vl, ph[ks], acc[mt]);
      }
    }
    __builtin_amdgcn_s_setprio(0);
    SFENCE(); SBARM();
  }

  // ---- epilogue: 1/l is lane-local (col q = l15)
  {
    const float inv = 1.0f / lsum;
    const size_t obase = (size_t)(b * SEQ + q0 + w * 16 + l15) * DM + h * 64;
#pragma unroll
    for (int mt = 0; mt < 4; ++mt) {
      u16x4 ov;
#pragma unroll
      for (int r = 0; r < 4; ++r) ov[r] = f2bf(acc[mt][r] * inv);
      *(u16x4*)&ohi[obase + mt * 16 + quad * 4] = ov;
    }
  }
}

// ---------------------------------------------------------------------------
// Launch
// ---------------------------------------------------------------------------
extern "C" void kernel_launch(void* const* d_in, const int* in_sizes, int n_in,
                              void* d_out, int out_size, void* d_ws, size_t ws_size,
                              hipStream_t stream) {
  const float* x    = (const float*)d_in[0];
  const float* Wq   = (const float*)d_in[1];
  const float* Wk   = (const float*)d_in[2];
  const float* Wv   = (const float*)d_in[3];
  const float* Wo   = (const float*)d_in[4];
  const float* qn_w = (const float*)d_in[5];
  const float* kn_w = (const float*)d_in[6];
  const float* Mk   = (const float*)d_in[7];
  const float* Mtk  = (const float*)d_in[8];
  const float* Ck   = (const float*)d_in[9];
  const float* Mv   = (const float*)d_in[10];
  const float* Mtv  = (const float*)d_in[11];
  const float* Cv   = (const float*)d_in[12];
  float* out = (float*)d_out;

  const size_t MBb = 1024ull * 1024ull;
  const size_t SEG = (size_t)DM * DM;  // 4 Mi elements
  char* w = (char*)d_ws;
  float* qb = (float*)(w + 0 * MBb);        // 16 MB each
  float* kb = (float*)(w + 16 * MBb);
  float* vb = (float*)(w + 32 * MBb);
  unsigned short* xhi     = (unsigned short*)(w + 48 * MBb);  // 8 MB each
  unsigned short* xlo     = (unsigned short*)(w + 56 * MBb);
  unsigned short* wcat_hi = (unsigned short*)(w + 64 * MBb);  // 24 MB [6144][2048]
  unsigned short* wcat_lo = (unsigned short*)(w + 88 * MBb);  // 24 MB
  unsigned short* wot     = (unsigned short*)(w + 112 * MBb); // 8 MB
  // Reuse (stream-ordered death):
  unsigned short* q_hi  = wcat_hi;            // seg0 dead after qkv gemm
  unsigned short* k_hi  = wcat_hi + SEG;
  unsigned short* k_lo  = wcat_hi + 2 * SEG;
  unsigned short* q_lo  = wcat_lo;
  unsigned short* vt_hi = wcat_lo + SEG;
  unsigned short* vt_lo = wcat_lo + 2 * SEG;
  unsigned short* o_hi  = xhi;                // x dead after qkv gemm
  float* opart = (float*)(w + 0 * MBb);       // 32 MB; qb/kb dead by out-GEMM

  const int n8 = (NROWS * DM) / 8;

  split_convert_kernel<<<n8 / 256, 256, 0, stream>>>(x, xhi, xlo, n8);
  transpose_split_batch_kernel<<<dim3(DM / 64, DM / 64, 4), 256, 0, stream>>>(
      Wq, Wk, Wv, Wo,
      wcat_hi, wcat_hi + SEG, wcat_lo + SEG, wcat_hi + 2 * SEG, wcat_lo + 2 * SEG, wot);

  qkv_gemm_kernel<<<dim3(3 * DM / 256, NROWS / 128), 256, 0, stream>>>(
      xhi, xlo, wcat_hi, wcat_lo, qb, kb, vb);

  rmsnorm_kernel<<<NROWS, 256, 0, stream>>>(kb, kn_w);
  // fold 1/8 (score scale) AND log2(e) (exp2 softmax domain) into q
  rmsnorm_split_kernel<<<NROWS, 256, 0, stream>>>(
      qb, qn_w, q_hi, q_lo, 0.125f * 1.4426950408889634f);

  quant_kernel<true ><<<NVEC / 256, 256, 0, stream>>>(kb, Mk, Mtk, Ck, k_hi, k_lo);
  quant_kernel<false><<<NVEC / 256, 256, 0, stream>>>(vb, Mv, Mtv, Cv, nullptr, nullptr);
  vt_split_kernel<<<dim3(SEQ / 64, BATCH * HEADS), 256, 0, stream>>>(vb, vt_hi, vt_lo);

  attn_mfma_kernel<<<dim3(BATCH * HEADS, SEQ / 64), 256, 0, stream>>>(
      q_hi, q_lo, k_hi, k_lo, vt_hi, vt_lo, o_hi);

  gemm_out_splitk_kernel<<<dim3(DM / 128, NROWS / 128, 2), 256, 0, stream>>>(
      o_hi, wot, opart);
  add2_f4_kernel<<<(NROWS * DM / 4 + 255) / 256, 256, 0, stream>>>(
      opart, opart + (size_t)NROWS * DM, out, NROWS * DM / 4);
}

// Round 8
// 411.929 us; speedup vs baseline: 1.0839x; 1.0839x over previous
//
#include <hip/hip_runtime.h>
#include <hip/hip_bf16.h>
#include <math.h>

// Problem constants (fixed by the reference)
#define HEADS 32
#define DIM_HEAD 64
#define DM 2048          // HEADS * DIM_HEAD
#define BATCH 2
#define SEQ 1024
#define NROWS (BATCH * SEQ)      // 2048 rows of DM
#define NVEC (NROWS * HEADS)     // 65536 per-head vectors
#define N_GROUPS 22
#define N_LEVELS 8
#define EPS_NORM 1e-8f
#define EPS_RMS 1e-6f

typedef float f32x4 __attribute__((ext_vector_type(4)));
typedef __bf16 bf16x8 __attribute__((ext_vector_type(8)));
typedef unsigned short u16x8 __attribute__((ext_vector_type(8)));
typedef unsigned short u16x4 __attribute__((ext_vector_type(4)));

// base-2 exp: v_exp_f32 is natively 2^x on gfx950
#if __has_builtin(__builtin_amdgcn_exp2f)
#define EXP2F(x) __builtin_amdgcn_exp2f(x)
#else
#define EXP2F(x) exp2f(x)
#endif

__device__ __forceinline__ unsigned short f2bf(float x) {
  union { float f; unsigned u; } v; v.f = x;
  unsigned r = v.u + 0x7fffu + ((v.u >> 16) & 1u);  // RTN-even
  return (unsigned short)(r >> 16);
}
__device__ __forceinline__ float bf2f(unsigned short h) {
  union { unsigned u; float f; } v; v.u = ((unsigned)h) << 16;
  return v.f;
}
__device__ __forceinline__ bf16x8 ldfrag(const unsigned short* p) {
  return __builtin_bit_cast(bf16x8, *(const u16x8*)p);
}
#define MFMA16(a, b, c) __builtin_amdgcn_mfma_f32_16x16x32_bf16((a), (b), (c), 0, 0, 0)

__device__ __forceinline__ void stage16(const unsigned short* g, unsigned short* lds) {
  __builtin_amdgcn_global_load_lds(
      (const __attribute__((address_space(1))) unsigned int*)g,
      (__attribute__((address_space(3))) unsigned int*)lds, 16, 0, 0);
}

// Pipeline control (attention): raw barrier, counted vmcnt, sched fence.
#define WAITV(N) asm volatile("s_waitcnt vmcnt(" #N ")" ::: "memory")
#define SBARM()  asm volatile("s_barrier" ::: "memory")
#define SFENCE() __builtin_amdgcn_sched_barrier(0)

// ---------------------------------------------------------------------------
// fp32 -> bf16 hi/lo split (lo optional), 8 elements/thread
// ---------------------------------------------------------------------------
__global__ __launch_bounds__(256) void split_convert_kernel(
    const float* __restrict__ X, unsigned short* __restrict__ hi,
    unsigned short* __restrict__ lo, int n8) {
  const int i = blockIdx.x * 256 + threadIdx.x;
  if (i >= n8) return;
  const float4 a = ((const float4*)X)[2 * i];
  const float4 b = ((const float4*)X)[2 * i + 1];
  const float v[8] = {a.x, a.y, a.z, a.w, b.x, b.y, b.z, b.w};
  u16x8 h, l;
#pragma unroll
  for (int j = 0; j < 8; ++j) {
    const unsigned short hh = f2bf(v[j]);
    h[j] = hh;
    l[j] = f2bf(v[j] - bf2f(hh));
  }
  ((u16x8*)hi)[i] = h;
  if (lo) ((u16x8*)lo)[i] = l;
}

// ---------------------------------------------------------------------------
// Batched weight transpose+split: W [K][M] fp32 -> T [M][K] bf16 hi(/lo).
// grid (M/64, K/64, 4): z selects {Wq, Wk, Wv, Wo}.
// ---------------------------------------------------------------------------
__global__ __launch_bounds__(256) void transpose_split_batch_kernel(
    const float* __restrict__ W0, const float* __restrict__ W1,
    const float* __restrict__ W2, const float* __restrict__ W3,
    unsigned short* __restrict__ T0h, unsigned short* __restrict__ T1h,
    unsigned short* __restrict__ T1l, unsigned short* __restrict__ T2h,
    unsigned short* __restrict__ T2l, unsigned short* __restrict__ T3h) {
  const int z = blockIdx.z;
  const float* W = (z == 0) ? W0 : (z == 1) ? W1 : (z == 2) ? W2 : W3;
  unsigned short* Th = (z == 0) ? T0h : (z == 1) ? T1h : (z == 2) ? T2h : T3h;
  unsigned short* Tl = (z == 1) ? T1l : (z == 2) ? T2l : nullptr;

  __shared__ float S[64][65];
  const int t = threadIdx.x;
  const int tk = blockIdx.y * 64, tm = blockIdx.x * 64;
  {
    const int r = t >> 2, cs = (t & 3) * 16;
    const float* src = W + (size_t)(tk + r) * DM + tm + cs;
#pragma unroll
    for (int j = 0; j < 16; j += 4) {
      float4 v = *(const float4*)(src + j);
      S[r][cs + j] = v.x; S[r][cs + j + 1] = v.y;
      S[r][cs + j + 2] = v.z; S[r][cs + j + 3] = v.w;
    }
  }
  __syncthreads();
  const int m = t >> 2, ks = (t & 3) * 16;
  u16x8 h0, h1, l0, l1;
#pragma unroll
  for (int j = 0; j < 8; ++j) {
    const float v = S[ks + j][m];
    const unsigned short hh = f2bf(v);
    h0[j] = hh; l0[j] = f2bf(v - bf2f(hh));
  }
#pragma unroll
  for (int j = 0; j < 8; ++j) {
    const float v = S[ks + 8 + j][m];
    const unsigned short hh = f2bf(v);
    h1[j] = hh; l1[j] = f2bf(v - bf2f(hh));
  }
  const size_t o = (size_t)(tm + m) * DM + tk + ks;
  *(u16x8*)&Th[o] = h0; *(u16x8*)&Th[o + 8] = h1;
  if (Tl) { *(u16x8*)&Tl[o] = l0; *(u16x8*)&Tl[o + 8] = l1; }
}

// ---------------------------------------------------------------------------
// Fused QKV GEMM: A[N=2048][K=2048] @ Bcat[M=6144][K]^T.
// Segments: 0..2047 Wq^T (plain), 2048..4095 Wk^T, 4096..6143 Wv^T (split).
// ROUND-0 STRUCTURE RESTORED (verified best: ~122 µs, MfmaUtil 43%,
// 0 conflicts, 3 blocks/CU). Round-7's 128x256 tile regressed (occupancy
// 28->14%): the cross-block wave overlap matters more than LDS-read ratio.
// ---------------------------------------------------------------------------
__global__ __launch_bounds__(256) void qkv_gemm_kernel(
    const unsigned short* __restrict__ Ahi, const unsigned short* __restrict__ Alo,
    const unsigned short* __restrict__ Bhi, const unsigned short* __restrict__ Blo,
    float* __restrict__ q, float* __restrict__ k, float* __restrict__ v) {
  __shared__ unsigned short lAhi[128 * 32];
  __shared__ unsigned short lBhi[128 * 32];
  __shared__ unsigned short lAlo[128 * 32];
  __shared__ unsigned short lBlo[128 * 32];

  const int t = threadIdx.x;
  const int lane = t & 63, wave = t >> 6;
  const int wr = wave >> 1, wc = wave & 1;
  const int gm0 = blockIdx.y * 128;
  const int gnc = blockIdx.x * 128;
  const int seg = gnc >> 11;
  const bool split = (seg != 0);
  const int lrsub = lane >> 2;
  const int lcsub = lane & 3;

  f32x4 acc[4][4] = {};

  for (int kt = 0; kt < DM; kt += 32) {
    __syncthreads();
#pragma unroll
    for (int rg = wave; rg < 8; rg += 4) {
      const int lrow = rg * 16 + lrsub;
      const int c = lcsub ^ ((lrow >> 1) & 3);
      const size_t goffA = (size_t)(gm0 + lrow) * DM + kt + c * 8;
      const size_t goffB = (size_t)(gnc + lrow) * DM + kt + c * 8;
      stage16(Ahi + goffA, lAhi + rg * 512);
      stage16(Bhi + goffB, lBhi + rg * 512);
      if (split) {
        stage16(Alo + goffA, lAlo + rg * 512);
        stage16(Blo + goffB, lBlo + rg * 512);
      }
    }
    __syncthreads();

    bf16x8 ah[4], bh[4], al[4], bl[4];
#pragma unroll
    for (int i = 0; i < 4; ++i) {
      const int mrow = wr * 64 + i * 16 + (lane & 15);
      const int offa = mrow * 32 + (((lane >> 4) ^ ((mrow >> 1) & 3)) << 3);
      ah[i] = ldfrag(&lAhi[offa]);
      const int nrow = wc * 64 + i * 16 + (lane & 15);
      const int offb = nrow * 32 + (((lane >> 4) ^ ((nrow >> 1) & 3)) << 3);
      bh[i] = ldfrag(&lBhi[offb]);
      if (split) {
        al[i] = ldfrag(&lAlo[offa]);
        bl[i] = ldfrag(&lBlo[offb]);
      }
    }
#pragma unroll
    for (int i = 0; i < 4; ++i)
#pragma unroll
      for (int j = 0; j < 4; ++j) {
        acc[i][j] = MFMA16(ah[i], bh[j], acc[i][j]);
        if (split) {
          acc[i][j] = MFMA16(ah[i], bl[j], acc[i][j]);
          acc[i][j] = MFMA16(al[i], bh[j], acc[i][j]);
        }
      }
  }

  float* C = (seg == 0) ? q : (seg == 1) ? k : v;
  const int gn0 = gnc & 2047;
#pragma unroll
  for (int i = 0; i < 4; ++i) {
    const int row = gm0 + wr * 64 + i * 16 + ((lane >> 4) << 2);
#pragma unroll
    for (int j = 0; j < 4; ++j) {
      const int col = gn0 + wc * 64 + j * 16 + (lane & 15);
#pragma unroll
      for (int r = 0; r < 4; ++r)
        C[(size_t)(row + r) * DM + col] = acc[i][j][r];
    }
  }
}

// ---------------------------------------------------------------------------
// Output projection, split-K=2 (plain bf16), partials into Cpart.
// ---------------------------------------------------------------------------
__global__ __launch_bounds__(256) void gemm_out_splitk_kernel(
    const unsigned short* __restrict__ Ahi, const unsigned short* __restrict__ Bt,
    float* __restrict__ Cpart) {
  __shared__ unsigned short lAhi[128 * 32];
  __shared__ unsigned short lBhi[128 * 32];

  const int t = threadIdx.x;
  const int lane = t & 63, wave = t >> 6;
  const int wr = wave >> 1, wc = wave & 1;
  const int gm0 = blockIdx.y * 128, gn0 = blockIdx.x * 128;
  const int z = blockIdx.z;
  const int k0 = z * (DM / 2);
  const int lrsub = lane >> 2;
  const int lcsub = lane & 3;

  f32x4 acc[4][4] = {};

  for (int kt = k0; kt < k0 + DM / 2; kt += 32) {
    __syncthreads();
#pragma unroll
    for (int rg = wave; rg < 8; rg += 4) {
      const int lrow = rg * 16 + lrsub;
      const int c = lcsub ^ ((lrow >> 1) & 3);
      stage16(Ahi + (size_t)(gm0 + lrow) * DM + kt + c * 8, lAhi + rg * 512);
      stage16(Bt + (size_t)(gn0 + lrow) * DM + kt + c * 8, lBhi + rg * 512);
    }
    __syncthreads();

    bf16x8 ah[4], bh[4];
#pragma unroll
    for (int i = 0; i < 4; ++i) {
      const int mrow = wr * 64 + i * 16 + (lane & 15);
      ah[i] = ldfrag(&lAhi[mrow * 32 + (((lane >> 4) ^ ((mrow >> 1) & 3)) << 3)]);
      const int nrow = wc * 64 + i * 16 + (lane & 15);
      bh[i] = ldfrag(&lBhi[nrow * 32 + (((lane >> 4) ^ ((nrow >> 1) & 3)) << 3)]);
    }
#pragma unroll
    for (int i = 0; i < 4; ++i)
#pragma unroll
      for (int j = 0; j < 4; ++j)
        acc[i][j] = MFMA16(ah[i], bh[j], acc[i][j]);
  }

  float* C = Cpart + (size_t)z * NROWS * DM;
#pragma unroll
  for (int i = 0; i < 4; ++i) {
    const int row = gm0 + wr * 64 + i * 16 + ((lane >> 4) << 2);
#pragma unroll
    for (int j = 0; j < 4; ++j) {
      const int col = gn0 + wc * 64 + j * 16 + (lane & 15);
#pragma unroll
      for (int r = 0; r < 4; ++r)
        C[(size_t)(row + r) * DM + col] = acc[i][j][r];
    }
  }
}

__global__ __launch_bounds__(256) void add2_f4_kernel(
    const float* __restrict__ a, const float* __restrict__ b,
    float* __restrict__ o, int n4) {
  const int i = blockIdx.x * 256 + threadIdx.x;
  if (i >= n4) return;
  const float4 x = ((const float4*)a)[i];
  const float4 y = ((const float4*)b)[i];
  ((float4*)o)[i] = make_float4(x.x + y.x, x.y + y.y, x.z + y.z, x.w + y.w);
}

// ---------------------------------------------------------------------------
// Wave reductions
// ---------------------------------------------------------------------------
__device__ __forceinline__ float wave_sum(float x) {
#pragma unroll
  for (int o = 32; o > 0; o >>= 1) x += __shfl_xor(x, o, 64);
  return x;
}

// ---------------------------------------------------------------------------
// RotorQuant roundtrip core: h[66] normalized in/out (dequant * 1), in regs.
// ---------------------------------------------------------------------------
__device__ __forceinline__ float qnearest(float v, const float* __restrict__ C) {
  float best = C[0];
  float bd = fabsf(v - C[0]);
#pragma unroll
  for (int i = 1; i < N_LEVELS; ++i) {
    float d = fabsf(v - C[i]);
    if (d < bd) { bd = d; best = C[i]; }
  }
  return best;
}

__device__ __forceinline__ void rotor_roundtrip(
    float* __restrict__ h, const float* __restrict__ M,
    const float* __restrict__ Mt, const float* __restrict__ C) {
#pragma unroll
  for (int g = 0; g < N_GROUPS; ++g) {
    const float* Mg  = M  + g * 9;
    const float* Mtg = Mt + g * 9;
    const float a0 = h[3 * g + 0], a1 = h[3 * g + 1], a2 = h[3 * g + 2];
    const float r0 = a0 * Mg[0] + a1 * Mg[3] + a2 * Mg[6];
    const float r1 = a0 * Mg[1] + a1 * Mg[4] + a2 * Mg[7];
    const float r2 = a0 * Mg[2] + a1 * Mg[5] + a2 * Mg[8];
    const float d0 = qnearest(r0, C);
    const float d1 = qnearest(r1, C);
    const float d2 = qnearest(r2, C);
    h[3 * g + 0] = d0 * Mtg[0] + d1 * Mtg[3] + d2 * Mtg[6];
    h[3 * g + 1] = d0 * Mtg[1] + d1 * Mtg[4] + d2 * Mtg[7];
    h[3 * g + 2] = d0 * Mtg[2] + d1 * Mtg[5] + d2 * Mtg[8];
  }
}

// ---------------------------------------------------------------------------
// RMSNorm -> bf16 hi/lo with extra post-scale (q path: folds 1/8 * log2e)
// ---------------------------------------------------------------------------
__global__ __launch_bounds__(256) void rmsnorm_split_kernel(
    const float* __restrict__ y, const float* __restrict__ w,
    unsigned short* __restrict__ hi, unsigned short* __restrict__ lo,
    float post) {
  __shared__ float rbuf[4];
  const int row = blockIdx.x;
  const float* p = y + (size_t)row * DM;
  const int t = threadIdx.x;
  const int wave = t >> 6, lane = t & 63;

  const int c0 = t * 8;
  float4 a = *(const float4*)(p + c0);
  float4 b = *(const float4*)(p + c0 + 4);
  float v[8] = {a.x, a.y, a.z, a.w, b.x, b.y, b.z, b.w};
  float ss = 0.f;
#pragma unroll
  for (int j = 0; j < 8; ++j) ss += v[j] * v[j];
  ss = wave_sum(ss);
  if (lane == 0) rbuf[wave] = ss;
  __syncthreads();
  ss = rbuf[0] + rbuf[1] + rbuf[2] + rbuf[3];
  const float scale = rsqrtf(ss * (1.0f / DM) + EPS_RMS) * post;

  u16x8 hv, lv;
#pragma unroll
  for (int j = 0; j < 8; ++j) {
    const float val = v[j] * scale * w[c0 + j];
    const unsigned short hh = f2bf(val);
    hv[j] = hh; lv[j] = f2bf(val - bf2f(hh));
  }
  *(u16x8*)&hi[(size_t)row * DM + c0] = hv;
  *(u16x8*)&lo[(size_t)row * DM + c0] = lv;
}

// ---------------------------------------------------------------------------
// FUSED (round 8): RMSNorm(k) + RotorQuant(k) -> bf16 hi/lo.
// One thread per head-vector (64 elems). A DM-row = 32 consecutive threads,
// so the row sum-of-squares is a 32-lane-group shfl_xor reduce. The scaled
// fp32 values never round-trip through HBM (saves 32 MB vs the 2-kernel
// flow; fp32 stores were exact, so results are identical up to fp32
// re-association in the row sum).
// ---------------------------------------------------------------------------
__global__ __launch_bounds__(256) void rms_quant_k_kernel(
    const float* __restrict__ kv, const float* __restrict__ w,
    const float* __restrict__ M, const float* __restrict__ Mt,
    const float* __restrict__ C,
    unsigned short* __restrict__ hi, unsigned short* __restrict__ lo) {
  const int vec = blockIdx.x * 256 + threadIdx.x;
  const float* p = kv + (size_t)vec * DIM_HEAD;
  const float* wv = w + (vec & 31) * 64;

  float h[66];
  float ssr = 0.f;
#pragma unroll
  for (int d = 0; d < DIM_HEAD; ++d) { h[d] = p[d]; ssr += h[d] * h[d]; }
  // full-row (DM=2048) sum of squares: reduce across the row's 32 threads
#pragma unroll
  for (int off = 1; off < 32; off <<= 1) ssr += __shfl_xor(ssr, off, 32);
  const float scale = rsqrtf(ssr * (1.0f / DM) + EPS_RMS);

  float ss = 0.f;
#pragma unroll
  for (int d = 0; d < DIM_HEAD; ++d) {
    h[d] = h[d] * scale * wv[d];
    ss += h[d] * h[d];
  }
  const float norm = fmaxf(sqrtf(ss), EPS_NORM);
  const float inv = 1.0f / norm;
#pragma unroll
  for (int d = 0; d < DIM_HEAD; ++d) h[d] *= inv;
  h[64] = 0.f; h[65] = 0.f;

  rotor_roundtrip(h, M, Mt, C);

#pragma unroll
  for (int g8 = 0; g8 < 8; ++g8) {
    u16x8 hv, lv;
#pragma unroll
    for (int j = 0; j < 8; ++j) {
      const float val = h[g8 * 8 + j] * norm;
      const unsigned short hh = f2bf(val);
      hv[j] = hh; lv[j] = f2bf(val - bf2f(hh));
    }
    *(u16x8*)&hi[(size_t)vec * DIM_HEAD + g8 * 8] = hv;
    *(u16x8*)&lo[(size_t)vec * DIM_HEAD + g8 * 8] = lv;
  }
}

// ---------------------------------------------------------------------------
// FUSED (round 8): RotorQuant(v) + V^T split -> vt hi/lo.
// Block = (bh, 128 s), 128 threads, one thread per head-vector. Dequantized
// fp32 values go to padded LDS [128][65] (conflict-free both sides), block
// transposes and writes vt[(bh*64+d)][s] bf16 hi/lo. Saves the 32 MB vb
// round-trip of the quant -> vt_split 2-kernel flow.
// ---------------------------------------------------------------------------
__global__ __launch_bounds__(128) void quant_vt_kernel(
    const float* __restrict__ vsrc, const float* __restrict__ M,
    const float* __restrict__ Mt, const float* __restrict__ C,
    unsigned short* __restrict__ hi, unsigned short* __restrict__ lo) {
  __shared__ float T[128][65];
  const int bh = blockIdx.y;              // 0..63
  const int b = bh >> 5, hh = bh & 31;
  const int s0 = blockIdx.x * 128;
  const int t = threadIdx.x;              // 0..127

  {
    const int s = s0 + t;
    const float* p = vsrc + ((size_t)(b * SEQ + s) * DM + hh * 64);
    float h[66];
    float ss = 0.f;
#pragma unroll
    for (int d = 0; d < DIM_HEAD; ++d) { h[d] = p[d]; ss += h[d] * h[d]; }
    const float norm = fmaxf(sqrtf(ss), EPS_NORM);
    const float inv = 1.0f / norm;
#pragma unroll
    for (int d = 0; d < DIM_HEAD; ++d) h[d] *= inv;
    h[64] = 0.f; h[65] = 0.f;

    rotor_roundtrip(h, M, Mt, C);

#pragma unroll
    for (int d = 0; d < DIM_HEAD; ++d) T[t][d] = h[d] * norm;
  }
  __syncthreads();

  // transpose + split: thread -> d = t&63, s-half = (t>>6)*64
  const int d = t & 63, sh = (t >> 6) * 64;
  const size_t o = (size_t)(bh * 64 + d) * SEQ + s0 + sh;
#pragma unroll
  for (int seg = 0; seg < 8; ++seg) {
    u16x8 hv, lv;
#pragma unroll
    for (int j = 0; j < 8; ++j) {
      const float val = T[sh + seg * 8 + j][d];
      const unsigned short hb = f2bf(val);
      hv[j] = hb; lv[j] = f2bf(val - bf2f(hb));
    }
    *(u16x8*)&hi[o + seg * 8] = hv;
    *(u16x8*)&lo[o + seg * 8] = lv;
  }
}

// ---------------------------------------------------------------------------
// MFMA flash attention, split-bf16. Block = (b,h,64 q rows), 256 threads.
// Swapped QK^T (S^T layout, lane-local softmax), conflict-free P-LDS,
// exp2 domain, K/V dbuf + counted vmcnt + raw barriers. 80 KB LDS.
// (round-6 verified: 441 µs end-to-end, attn no longer top dispatch)
// ---------------------------------------------------------------------------
__global__ __launch_bounds__(256) void attn_mfma_kernel(
    const unsigned short* __restrict__ qhi, const unsigned short* __restrict__ qlo,
    const unsigned short* __restrict__ khi, const unsigned short* __restrict__ klo,
    const unsigned short* __restrict__ vthi, const unsigned short* __restrict__ vtlo,
    unsigned short* __restrict__ ohi) {
  __shared__ unsigned short Ks_h[2][4096], Ks_l[2][4096];   // [buf][64 key][64 d]
  __shared__ unsigned short Vt_h[2][4096], Vt_l[2][4096];   // [buf][64 d][64 s]
  __shared__ unsigned int   Ps[4096];                       // [4 w][16 q][64 key]

  const int bh = blockIdx.x;        // 0..63  (XCD = bh % 8 -> L2 locality)
  const int qt = blockIdx.y;        // 0..15
  const int h = bh & 31, b = bh >> 5;
  const int q0 = qt * 64;
  const int t = threadIdx.x, lane = t & 63, w = t >> 6;
  const int quad = lane >> 4, l15 = lane & 15;
  const int srow = lane >> 3, schunk = lane & 7;
  const int pswz = (l15 & 7) << 2;            // P swizzle (words, 16B-multiple)
  unsigned int* Psw = Ps + w * 1024;          // wave-private [16][64] u32

  auto stage = [&](const unsigned short* g, int stride, unsigned short* arr) {
#pragma unroll
    for (int it = 0; it < 2; ++it) {
      const int r = w * 16 + it * 8 + srow;
      const int c = schunk ^ (r & 7);
      stage16(g + (size_t)r * stride + c * 8, arr + (w * 16 + it * 8) * 64);
    }
  };

  const unsigned short* gkh = khi + ((size_t)(b * SEQ) * DM + h * 64);
  const unsigned short* gkl = klo + ((size_t)(b * SEQ) * DM + h * 64);
  const unsigned short* gvh = vthi + (size_t)(bh * 64) * SEQ;
  const unsigned short* gvl = vtlo + (size_t)(bh * 64) * SEQ;

  auto stageAll = [&](int kt, int buf) {
    stage(gkh + (size_t)kt * DM, DM, Ks_h[buf]);
    stage(gkl + (size_t)kt * DM, DM, Ks_l[buf]);
    stage(gvh + kt, SEQ, Vt_h[buf]);
    stage(gvl + kt, SEQ, Vt_l[buf]);
  };

  // Q frags (B-operand of swapped QK: col n = l15 = q row; same lane map)
  bf16x8 qh[2], ql[2];
  {
    const size_t qrow = (size_t)(b * SEQ + q0 + w * 16 + l15) * DM + h * 64;
#pragma unroll
    for (int ks = 0; ks < 2; ++ks) {
      qh[ks] = ldfrag(&qhi[qrow + ks * 32 + quad * 8]);
      ql[ks] = ldfrag(&qlo[qrow + ks * 32 + quad * 8]);
    }
  }

  f32x4 acc[4] = {};               // O^T: row d = mt*16+quad*4+r, col q = l15
  float m_prev = -INFINITY;        // per-lane (q = l15); replicated across quads
  float lsum = 0.f;

  stageAll(0, 0);

  for (int tt = 0; tt < 16; ++tt) {
    const int c = tt & 1, n = c ^ 1;
    if (tt < 15) {
      stageAll((tt + 1) * 64, n);
      WAITV(8);
    } else {
      WAITV(0);
    }
    SBARM(); SFENCE();
    const unsigned short* cKh = Ks_h[c];
    const unsigned short* cKl = Ks_l[c];
    const unsigned short* cVh = Vt_h[c];
    const unsigned short* cVl = Vt_l[c];

    // ---- S^T = K @ Q (swapped), split: Kh*Qh + Kl*Qh + Kh*Ql
    f32x4 s[4] = {};
    __builtin_amdgcn_s_setprio(1);
#pragma unroll
    for (int nt = 0; nt < 4; ++nt) {
#pragma unroll
      for (int ks = 0; ks < 2; ++ks) {
        const int row = nt * 16 + l15;
        const int off = row * 64 + (((quad + 4 * ks) ^ (row & 7)) << 3);
        const bf16x8 kh = ldfrag(&cKh[off]);
        const bf16x8 kl = ldfrag(&cKl[off]);
        s[nt] = MFMA16(kh, qh[ks], s[nt]);
        s[nt] = MFMA16(kl, qh[ks], s[nt]);
        s[nt] = MFMA16(kh, ql[ks], s[nt]);
      }
    }
    __builtin_amdgcn_s_setprio(0);

    // ---- online softmax, lane-local over 16 keys + 2 cross-quad shuffles
    float mx = s[0][0];
#pragma unroll
    for (int nt = 0; nt < 4; ++nt)
#pragma unroll
      for (int r = 0; r < 4; ++r) mx = fmaxf(mx, s[nt][r]);
    mx = fmaxf(mx, __shfl_xor(mx, 16, 64));
    mx = fmaxf(mx, __shfl_xor(mx, 32, 64));
    const float mn = fmaxf(m_prev, mx);
    const float al = EXP2F(m_prev - mn);
    float rs = 0.f;
#pragma unroll
    for (int nt = 0; nt < 4; ++nt)
#pragma unroll
      for (int r = 0; r < 4; ++r) {
        const float e = EXP2F(s[nt][r] - mn);
        s[nt][r] = e; rs += e;
      }
    rs += __shfl_xor(rs, 16, 64);
    rs += __shfl_xor(rs, 32, 64);
    lsum = lsum * al + rs;
    m_prev = mn;
#pragma unroll
    for (int mt = 0; mt < 4; ++mt) acc[mt] *= al;   // acc col q = l15: lane-local

    // ---- P store: row = q (l15), col = key = nt*16 + quad*4 + r, packed
    //      hi|lo u32, one b128 per nt, swizzled col ^ pswz (conflict-free)
#pragma unroll
    for (int nt = 0; nt < 4; ++nt) {
      uint4 pw;
      unsigned int* wp = (unsigned int*)&pw;
#pragma unroll
      for (int r = 0; r < 4; ++r) {
        const unsigned short hb = f2bf(s[nt][r]);
        const unsigned short lb = f2bf(s[nt][r] - bf2f(hb));
        wp[r] = ((unsigned)hb << 16) | (unsigned)lb;
      }
      const int cb = (nt * 16 + quad * 4) ^ pswz;
      *(uint4*)&Psw[l15 * 64 + cb] = pw;
    }

    // ---- P load as B-frag (col q = l15, k = key = ks*32 + quad*8 + j)
    bf16x8 ph[2], pl[2];
#pragma unroll
    for (int ks = 0; ks < 2; ++ks) {
      const int c0 = (ks * 32 + quad * 8) ^ pswz;
      const int c1 = (ks * 32 + quad * 8 + 4) ^ pswz;
      const uint4 pa = *(const uint4*)&Psw[l15 * 64 + c0];
      const uint4 pb = *(const uint4*)&Psw[l15 * 64 + c1];
      u16x8 hv, lv;
      const unsigned int pw[8] = {pa.x, pa.y, pa.z, pa.w, pb.x, pb.y, pb.z, pb.w};
#pragma unroll
      for (int j = 0; j < 8; ++j) {
        hv[j] = (unsigned short)(pw[j] >> 16);
        lv[j] = (unsigned short)(pw[j] & 0xffffu);
      }
      ph[ks] = __builtin_bit_cast(bf16x8, hv);
      pl[ks] = __builtin_bit_cast(bf16x8, lv);
    }

    // ---- O^T += V^T @ P  (A = Vt frags, B = P frags)
    __builtin_amdgcn_s_setprio(1);
#pragma unroll
    for (int mt = 0; mt < 4; ++mt) {
#pragma unroll
      for (int ks = 0; ks < 2; ++ks) {
        const int drow = mt * 16 + l15;
        const int offv = drow * 64 + (((quad + 4 * ks) ^ (drow & 7)) << 3);
        const bf16x8 vh = ldfrag(&cVh[offv]);
        const bf16x8 vl = ldfrag(&cVl[offv]);
        acc[mt] = MFMA16(vh, ph[ks], acc[mt]);
        acc[mt] = MFMA16(vh, pl[ks], acc[mt]);
        acc[mt] = MFMA16(vl, ph[ks], acc[mt]);
      }
    }
    __builtin_amdgcn_s_setprio(0);
    SFENCE(); SBARM();
  }

  // ---- epilogue: 1/l is lane-local (col q = l15)
  {
    const float inv = 1.0f / lsum;
    const size_t obase = (size_t)(b * SEQ + q0 + w * 16 + l15) * DM + h * 64;
#pragma unroll
    for (int mt = 0; mt < 4; ++mt) {
      u16x4 ov;
#pragma unroll
      for (int r = 0; r < 4; ++r) ov[r] = f2bf(acc[mt][r] * inv);
      *(u16x4*)&ohi[obase + mt * 16 + quad * 4] = ov;
    }
  }
}

// ---------------------------------------------------------------------------
// Launch
// ---------------------------------------------------------------------------
extern "C" void kernel_launch(void* const* d_in, const int* in_sizes, int n_in,
                              void* d_out, int out_size, void* d_ws, size_t ws_size,
                              hipStream_t stream) {
  const float* x    = (const float*)d_in[0];
  const float* Wq   = (const float*)d_in[1];
  const float* Wk   = (const float*)d_in[2];
  const float* Wv   = (const float*)d_in[3];
  const float* Wo   = (const float*)d_in[4];
  const float* qn_w = (const float*)d_in[5];
  const float* kn_w = (const float*)d_in[6];
  const float* Mk   = (const float*)d_in[7];
  const float* Mtk  = (const float*)d_in[8];
  const float* Ck   = (const float*)d_in[9];
  const float* Mv   = (const float*)d_in[10];
  const float* Mtv  = (const float*)d_in[11];
  const float* Cv   = (const float*)d_in[12];
  float* out = (float*)d_out;

  const size_t MBb = 1024ull * 1024ull;
  const size_t SEG = (size_t)DM * DM;  // 4 Mi elements
  char* w = (char*)d_ws;
  float* qb = (float*)(w + 0 * MBb);        // 16 MB each
  float* kb = (float*)(w + 16 * MBb);
  float* vb = (float*)(w + 32 * MBb);
  unsigned short* xhi     = (unsigned short*)(w + 48 * MBb);  // 8 MB each
  unsigned short* xlo     = (unsigned short*)(w + 56 * MBb);
  unsigned short* wcat_hi = (unsigned short*)(w + 64 * MBb);  // 24 MB [6144][2048]
  unsigned short* wcat_lo = (unsigned short*)(w + 88 * MBb);  // 24 MB
  unsigned short* wot     = (unsigned short*)(w + 112 * MBb); // 8 MB
  // Reuse (stream-ordered death):
  unsigned short* q_hi  = wcat_hi;            // seg0 dead after qkv gemm
  unsigned short* k_hi  = wcat_hi + SEG;
  unsigned short* k_lo  = wcat_hi + 2 * SEG;
  unsigned short* q_lo  = wcat_lo;
  unsigned short* vt_hi = wcat_lo + SEG;
  unsigned short* vt_lo = wcat_lo + 2 * SEG;
  unsigned short* o_hi  = xhi;                // x dead after qkv gemm
  float* opart = (float*)(w + 0 * MBb);       // 32 MB; qb/kb dead by out-GEMM

  const int n8 = (NROWS * DM) / 8;

  split_convert_kernel<<<n8 / 256, 256, 0, stream>>>(x, xhi, xlo, n8);
  transpose_split_batch_kernel<<<dim3(DM / 64, DM / 64, 4), 256, 0, stream>>>(
      Wq, Wk, Wv, Wo,
      wcat_hi, wcat_hi + SEG, wcat_lo + SEG, wcat_hi + 2 * SEG, wcat_lo + 2 * SEG, wot);

  qkv_gemm_kernel<<<dim3(3 * DM / 128, NROWS / 128), 256, 0, stream>>>(
      xhi, xlo, wcat_hi, wcat_lo, qb, kb, vb);

  // fused rmsnorm(k) + quant(k) -> bf16 hi/lo (no kb round-trip)
  rms_quant_k_kernel<<<NVEC / 256, 256, 0, stream>>>(
      kb, kn_w, Mk, Mtk, Ck, k_hi, k_lo);
  // fold 1/8 (score scale) AND log2(e) (exp2 softmax domain) into q
  rmsnorm_split_kernel<<<NROWS, 256, 0, stream>>>(
      qb, qn_w, q_hi, q_lo, 0.125f * 1.4426950408889634f);
  // fused quant(v) + V^T split (no vb round-trip)
  quant_vt_kernel<<<dim3(SEQ / 128, BATCH * HEADS), 128, 0, stream>>>(
      vb, Mv, Mtv, Cv, vt_hi, vt_lo);

  attn_mfma_kernel<<<dim3(BATCH * HEADS, SEQ / 64), 256, 0, stream>>>(
      q_hi, q_lo, k_hi, k_lo, vt_hi, vt_lo, o_hi);

  gemm_out_splitk_kernel<<<dim3(DM / 128, NROWS / 128, 2), 256, 0, stream>>>(
      o_hi, wot, opart);
  add2_f4_kernel<<<(NROWS * DM / 4 + 255) / 256, 256, 0, stream>>>(
      opart, opart + (size_t)NROWS * DM, out, NROWS * DM / 4);
}